// Round 17
// baseline (24236.490 us; speedup 1.0000x reference)
//
#include <hip/hip_runtime.h>
#include <math.h>

#define BATCH 4
#define SEQ 2048
#define DM 1024
#define NH 16
#define DH 64

typedef unsigned int u32;

// fp32 -> bf16 (RNE) -> fp32
__device__ __forceinline__ float rbf(float f) {
  union { u32 u; float f; } v; v.f = f;
  u32 lsb = (v.u >> 16) & 1u;
  v.u += 0x7FFFu + lsb;
  v.u &= 0xFFFF0000u;
  return v.f;
}

__device__ __forceinline__ float read_pos(const void* p, int s, int mode) {
  if (mode == 1) return (float)(int)(((const unsigned long long*)p)[s]);
  if (mode == 2) return ((const float*)p)[s];
  return (float)(((const int*)p)[s]);
}

__global__ void possniff_kernel(const u32* __restrict__ pw, int* __restrict__ mode) {
  int m = 0;
  if (pw[1] == 1u && pw[2] == 2u && pw[3] == 3u) m = 0;
  else if (pw[2] == 1u && pw[4] == 2u && pw[6] == 3u) m = 1;
  else if (pw[1] == 0x3F800000u) m = 2;
  *mode = m;
}

// ============================================================
// Projection: C[m][n] = sum_k bf16(A[m][k]) * bf16(W[n][k]), fp32 accum.
// mode 0: C[m*1024+n];  mode 1: QKV layout [B,H,S,64]
// ============================================================
__global__ __launch_bounds__(256) void proj_naive(const float* __restrict__ A,
                                                  const float* __restrict__ W,
                                                  float* __restrict__ C,
                                                  int mode) {
  const int n = blockIdx.x * 256 + threadIdx.x;  // 0..1023
  const int m = blockIdx.y;                      // 0..8191
  const float* a = A + (size_t)m * DM;
  const float* w = W + (size_t)n * DM;
  float s = 0.f;
  for (int k = 0; k < DM; k += 4) {
    float4 av = *(const float4*)(a + k);
    float4 wv = *(const float4*)(w + k);
    s += rbf(av.x) * rbf(wv.x) + rbf(av.y) * rbf(wv.y) +
         rbf(av.z) * rbf(wv.z) + rbf(av.w) * rbf(wv.w);
  }
  if (mode == 0) {
    C[(size_t)m * DM + n] = s;
  } else {
    int h = n >> 6, d = n & 63;
    int b = m >> 11, ss = m & 2047;
    C[((size_t)(b * NH + h) * SEQ + ss) * DH + d] = s;
  }
}

// ============================================================
// RoPE, c9 convention: interleaved pairs (2i,2i+1),
// ang = pos * 10000^(-i/32), SIGN-FLIPPED rotation:
//   r1 = x1*cos + x2*sin;  r2 = -x1*sin + x2*cos   (rotation by -ang)
// ============================================================
__global__ __launch_bounds__(256) void rope_c9(float* __restrict__ Q,
                                               float* __restrict__ K,
                                               const void* __restrict__ pos,
                                               const int* __restrict__ pmode) {
  int idx = blockIdx.x * blockDim.x + threadIdx.x;  // B*H*S*32
  int i = idx & 31;
  int s = (idx >> 5) & (SEQ - 1);
  int bh = idx >> 16;
  float p = read_pos(pos, s, *pmode);
  float inv = powf(10000.0f, -(float)i * (1.0f / 32.0f));
  float ang = p * inv;
  float c, sn;
  sincosf(ang, &c, &sn);
  size_t base = ((size_t)bh * SEQ + s) * DH + 2 * i;
  float q1 = Q[base], q2 = Q[base + 1];
  Q[base]     = q1 * c + q2 * sn;
  Q[base + 1] = -q1 * sn + q2 * c;
  float k1 = K[base], k2 = K[base + 1];
  K[base]     = k1 * c + k2 * sn;
  K[base + 1] = -k1 * sn + k2 * c;
}

// ============================================================
// Naive attention: one block per (q, bh). Two-pass softmax, fp32.
// ============================================================
__global__ __launch_bounds__(256) void attn_naive(const float* __restrict__ Q,
                                                  const float* __restrict__ K,
                                                  const float* __restrict__ V,
                                                  float* __restrict__ AO) {
  __shared__ float qrow[64];
  __shared__ float sc[SEQ];
  __shared__ float red[256];
  __shared__ float outp[4][64];

  const int q = blockIdx.x;    // 0..2047
  const int bh = blockIdx.y;   // 0..63
  const int tid = threadIdx.x;

  if (tid < 64) qrow[tid] = Q[((size_t)bh * SEQ + q) * DH + tid];
  __syncthreads();

  float lmax = -1e30f;
  for (int k = tid; k <= q; k += 256) {
    const float* kp = K + ((size_t)bh * SEQ + k) * DH;
    float s = 0.f;
    for (int d = 0; d < DH; d += 4) {
      float4 kv = *(const float4*)(kp + d);
      s += qrow[d] * kv.x + qrow[d + 1] * kv.y +
           qrow[d + 2] * kv.z + qrow[d + 3] * kv.w;
    }
    s *= 0.125f;
    sc[k] = s;
    lmax = fmaxf(lmax, s);
  }
  red[tid] = lmax;
  __syncthreads();
  for (int off = 128; off > 0; off >>= 1) {
    if (tid < off) red[tid] = fmaxf(red[tid], red[tid + off]);
    __syncthreads();
  }
  const float m = red[0];
  __syncthreads();

  float lsum = 0.f;
  for (int k = tid; k <= q; k += 256) {
    float p = expf(sc[k] - m);
    sc[k] = p;
    lsum += p;
  }
  red[tid] = lsum;
  __syncthreads();
  for (int off = 128; off > 0; off >>= 1) {
    if (tid < off) red[tid] += red[tid + off];
    __syncthreads();
  }
  const float l = red[0];

  const int part = tid >> 6;
  const int d = tid & 63;
  float acc = 0.f;
  for (int k = part; k <= q; k += 4)
    acc += sc[k] * V[((size_t)bh * SEQ + k) * DH + d];
  outp[part][d] = acc;
  __syncthreads();
  if (part == 0) {
    float o = (outp[0][d] + outp[1][d] + outp[2][d] + outp[3][d]) / l;
    int b = bh >> 4, h = bh & 15;
    AO[((size_t)b * SEQ + q) * DM + h * DH + d] = o;
  }
}

// ============================================================
extern "C" void kernel_launch(void* const* d_in, const int* in_sizes, int n_in,
                              void* d_out, int out_size, void* d_ws, size_t ws_size,
                              hipStream_t stream) {
  int xi = -1, pi = -1, widx[8], nw = 0;
  for (int i = 0; i < n_in; ++i) {
    if (in_sizes[i] == BATCH * SEQ * DM) xi = i;
    else if (in_sizes[i] == SEQ) pi = i;
    else if (in_sizes[i] == DM * DM && nw < 8) widx[nw++] = i;
  }
  if (xi < 0) xi = 0;
  if (pi < 0) pi = 1;

  const float* x   = (const float*)d_in[xi];
  const void*  pos = d_in[pi];
  const float* q_w = (const float*)d_in[widx[0]];
  const float* k_w = (const float*)d_in[widx[1]];
  const float* v_w = (const float*)d_in[widx[2]];
  const float* o_w = (const float*)d_in[widx[3]];
  float* out = (float*)d_out;

  const size_t elems = (size_t)BATCH * SEQ * DM;
  float* Q  = (float*)d_ws;
  float* Kb = Q + elems;
  float* Vb = Kb + elems;
  float* AO = Vb + elems;
  int* pmode = (int*)(AO + elems);   // within first 4*elems+... well inside ws

  hipLaunchKernelGGL(possniff_kernel, dim3(1), dim3(1), 0, stream,
                     (const u32*)pos, pmode);

  dim3 pgrid(DM / 256, BATCH * SEQ);  // (4, 8192)
  hipLaunchKernelGGL(proj_naive, pgrid, dim3(256), 0, stream, x, q_w, Q, 1);
  hipLaunchKernelGGL(proj_naive, pgrid, dim3(256), 0, stream, x, k_w, Kb, 1);
  hipLaunchKernelGGL(proj_naive, pgrid, dim3(256), 0, stream, x, v_w, Vb, 1);

  int rope_threads = BATCH * NH * SEQ * 32;
  hipLaunchKernelGGL(rope_c9, dim3(rope_threads / 256), dim3(256), 0, stream,
                     Q, Kb, pos, pmode);

  hipLaunchKernelGGL(attn_naive, dim3(SEQ, BATCH * NH), dim3(256), 0, stream,
                     Q, Kb, Vb, AO);

  hipLaunchKernelGGL(proj_naive, pgrid, dim3(256), 0, stream, AO, o_w, out, 0);
}

// Round 18
// 4809.610 us; speedup vs baseline: 5.0392x; 5.0392x over previous
//
#include <hip/hip_runtime.h>
#include <math.h>

#define BATCH 4
#define SEQ 2048
#define DM 1024
#define NH 16
#define DH 64

typedef unsigned int u32;
typedef unsigned short u16;
typedef __attribute__((ext_vector_type(8))) short bf16x8;
typedef __attribute__((ext_vector_type(8))) unsigned short u16x8;
typedef __attribute__((ext_vector_type(4))) float f32x4;

__device__ __forceinline__ float b2f(u16 h) {
  union { u32 u; float f; } v; v.u = ((u32)h) << 16; return v.f;
}
__device__ __forceinline__ u16 f2bf(float f) {
  union { u32 u; float f; } v; v.f = f;
  u32 lsb = (v.u >> 16) & 1u;
  v.u += 0x7FFFu + lsb;
  return (u16)(v.u >> 16);
}

__device__ __forceinline__ float read_pos(const void* p, int s, int mode) {
  if (mode == 1) return (float)(int)(((const unsigned long long*)p)[s]);
  if (mode == 2) return ((const float*)p)[s];
  return (float)(((const int*)p)[s]);
}

__global__ void possniff_kernel(const u32* __restrict__ pw, int* __restrict__ mode) {
  int m = 0;
  if (pw[1] == 1u && pw[2] == 2u && pw[3] == 3u) m = 0;
  else if (pw[2] == 1u && pw[4] == 2u && pw[6] == 3u) m = 1;
  else if (pw[1] == 0x3F800000u) m = 2;
  *mode = m;
}

// ============================================================
// fp32 -> bf16 conversion (vectorized, grid-stride)
// ============================================================
__global__ __launch_bounds__(256) void cvt_kernel(const float* __restrict__ in,
                                                  u16* __restrict__ out, int n4) {
  int i = blockIdx.x * 256 + threadIdx.x;
  int stride = gridDim.x * 256;
  for (; i < n4; i += stride) {
    float4 v = *(const float4*)(in + (size_t)i * 4);
    ushort4 o = make_ushort4(f2bf(v.x), f2bf(v.y), f2bf(v.z), f2bf(v.w));
    *(ushort4*)(out + (size_t)i * 4) = o;
  }
}

// ============================================================
// MFMA GEMM: C[M,N] = A[M,K] * W[N,K]^T, bf16 in, fp32 accum.
// m97 structure: 128x128 tile, BK=32, 4 waves (2x2), 4x4 frags/wave,
// global_load_lds width-16 staging.
// CMODE 0: fp32 C[m*1024+n]   CMODE 1: bf16 QKV layout [B,H,S,64]
// ============================================================
template<int CMODE>
__global__ __launch_bounds__(256) void gemm_mfma(const u16* __restrict__ A,
                                                 const u16* __restrict__ W,
                                                 float* __restrict__ Cf,
                                                 u16* __restrict__ Cb) {
  __shared__ u16 As[128 * 32];
  __shared__ u16 Bs[128 * 32];
  const int tid = threadIdx.x;
  const int wave = tid >> 6;
  const int lane = tid & 63;
  const int wm = wave >> 1;
  const int wn = wave & 1;
  const int n0 = blockIdx.x * 128;
  const int m0 = blockIdx.y * 128;

  const int fl = lane & 15;        // fragment row/col
  const int kq = lane >> 4;        // k-chunk selector (x8)
  const int s_r = lane >> 2;       // staging row within 16
  const int s_c = (lane & 3) * 8;  // staging col (u16 units)

  const u16* Ag = A + (size_t)m0 * DM;
  const u16* Wg = W + (size_t)n0 * DM;

  f32x4 acc[4][4] = {};

  for (int k0 = 0; k0 < DM; k0 += 32) {
    __syncthreads();
#pragma unroll
    for (int j = 0; j < 2; ++j) {
      int row = wave * 32 + j * 16 + s_r;
      __builtin_amdgcn_global_load_lds(
          (const __attribute__((address_space(1))) void*)(Ag + (size_t)row * DM + k0 + s_c),
          (__attribute__((address_space(3))) void*)(As + wave * 1024 + j * 512),
          16, 0, 0);
      __builtin_amdgcn_global_load_lds(
          (const __attribute__((address_space(1))) void*)(Wg + (size_t)row * DM + k0 + s_c),
          (__attribute__((address_space(3))) void*)(Bs + wave * 1024 + j * 512),
          16, 0, 0);
    }
    __syncthreads();

    bf16x8 af[4], bfr[4];
#pragma unroll
    for (int m = 0; m < 4; ++m)
      af[m] = *(const bf16x8*)&As[(wm * 64 + m * 16 + fl) * 32 + kq * 8];
#pragma unroll
    for (int n = 0; n < 4; ++n)
      bfr[n] = *(const bf16x8*)&Bs[(wn * 64 + n * 16 + fl) * 32 + kq * 8];
#pragma unroll
    for (int m = 0; m < 4; ++m)
#pragma unroll
      for (int n = 0; n < 4; ++n)
        acc[m][n] = __builtin_amdgcn_mfma_f32_16x16x32_bf16(af[m], bfr[n],
                                                            acc[m][n], 0, 0, 0);
  }

  // epilogue: D col = lane&15, row = (lane>>4)*4 + reg  [m89-verified]
#pragma unroll
  for (int m = 0; m < 4; ++m) {
#pragma unroll
    for (int n = 0; n < 4; ++n) {
      int gcol = n0 + wn * 64 + n * 16 + fl;
#pragma unroll
      for (int r = 0; r < 4; ++r) {
        int grow = m0 + wm * 64 + m * 16 + kq * 4 + r;
        float v = acc[m][n][r];
        if (CMODE == 0) {
          Cf[(size_t)grow * DM + gcol] = v;
        } else {
          int b = grow >> 11, s = grow & (SEQ - 1);
          int h = gcol >> 6, d = gcol & 63;
          Cb[((size_t)(b * NH + h) * SEQ + s) * DH + d] = f2bf(v);
        }
      }
    }
  }
}

// ============================================================
// RoPE, c9 convention (rotation by -ang), bf16 in/out, fp32 math.
// ============================================================
__global__ __launch_bounds__(256) void rope_c9(u16* __restrict__ Q,
                                               u16* __restrict__ K,
                                               const void* __restrict__ pos,
                                               const int* __restrict__ pmode) {
  int idx = blockIdx.x * blockDim.x + threadIdx.x;  // B*H*S*32
  int i = idx & 31;
  int s = (idx >> 5) & (SEQ - 1);
  int bh = idx >> 16;
  float p = read_pos(pos, s, *pmode);
  float inv = powf(10000.0f, -(float)i * (1.0f / 32.0f));
  float ang = p * inv;
  float c, sn;
  sincosf(ang, &c, &sn);
  size_t base = ((size_t)bh * SEQ + s) * DH + 2 * i;
  float q1 = b2f(Q[base]), q2 = b2f(Q[base + 1]);
  Q[base]     = f2bf(q1 * c + q2 * sn);
  Q[base + 1] = f2bf(-q1 * sn + q2 * c);
  float k1 = b2f(K[base]), k2 = b2f(K[base + 1]);
  K[base]     = f2bf(k1 * c + k2 * sn);
  K[base + 1] = f2bf(-k1 * sn + k2 * c);
}

// ============================================================
// Attention (unchanged algorithm), bf16 I/O, fp32 math.
// ============================================================
__global__ __launch_bounds__(256) void attn_naive(const u16* __restrict__ Q,
                                                  const u16* __restrict__ K,
                                                  const u16* __restrict__ V,
                                                  u16* __restrict__ AO) {
  __shared__ float qrow[64];
  __shared__ float sc[SEQ];
  __shared__ float red[256];
  __shared__ float outp[4][64];

  const int q = blockIdx.x;
  const int bh = blockIdx.y;
  const int tid = threadIdx.x;

  if (tid < 64) qrow[tid] = b2f(Q[((size_t)bh * SEQ + q) * DH + tid]);
  __syncthreads();

  float lmax = -1e30f;
  for (int k = tid; k <= q; k += 256) {
    const u16* kp = K + ((size_t)bh * SEQ + k) * DH;
    float s = 0.f;
    for (int d = 0; d < DH; d += 8) {
      u16x8 kv = *(const u16x8*)(kp + d);
      s += qrow[d + 0] * b2f(kv[0]) + qrow[d + 1] * b2f(kv[1]) +
           qrow[d + 2] * b2f(kv[2]) + qrow[d + 3] * b2f(kv[3]) +
           qrow[d + 4] * b2f(kv[4]) + qrow[d + 5] * b2f(kv[5]) +
           qrow[d + 6] * b2f(kv[6]) + qrow[d + 7] * b2f(kv[7]);
    }
    s *= 0.125f;
    sc[k] = s;
    lmax = fmaxf(lmax, s);
  }
  red[tid] = lmax;
  __syncthreads();
  for (int off = 128; off > 0; off >>= 1) {
    if (tid < off) red[tid] = fmaxf(red[tid], red[tid + off]);
    __syncthreads();
  }
  const float m = red[0];
  __syncthreads();

  float lsum = 0.f;
  for (int k = tid; k <= q; k += 256) {
    float p = expf(sc[k] - m);
    sc[k] = p;
    lsum += p;
  }
  red[tid] = lsum;
  __syncthreads();
  for (int off = 128; off > 0; off >>= 1) {
    if (tid < off) red[tid] += red[tid + off];
    __syncthreads();
  }
  const float l = red[0];

  const int part = tid >> 6;
  const int d = tid & 63;
  float acc = 0.f;
  for (int k = part; k <= q; k += 4)
    acc += sc[k] * b2f(V[((size_t)bh * SEQ + k) * DH + d]);
  outp[part][d] = acc;
  __syncthreads();
  if (part == 0) {
    float o = (outp[0][d] + outp[1][d] + outp[2][d] + outp[3][d]) / l;
    int b = bh >> 4, h = bh & 15;
    AO[((size_t)b * SEQ + q) * DM + h * DH + d] = f2bf(o);
  }
}

// ============================================================
extern "C" void kernel_launch(void* const* d_in, const int* in_sizes, int n_in,
                              void* d_out, int out_size, void* d_ws, size_t ws_size,
                              hipStream_t stream) {
  int xi = -1, pi = -1, widx[8], nw = 0;
  for (int i = 0; i < n_in; ++i) {
    if (in_sizes[i] == BATCH * SEQ * DM) xi = i;
    else if (in_sizes[i] == SEQ) pi = i;
    else if (in_sizes[i] == DM * DM && nw < 8) widx[nw++] = i;
  }
  if (xi < 0) xi = 0;
  if (pi < 0) pi = 1;

  const float* x   = (const float*)d_in[xi];
  const void*  pos = d_in[pi];
  const float* q_w = (const float*)d_in[widx[0]];
  const float* k_w = (const float*)d_in[widx[1]];
  const float* v_w = (const float*)d_in[widx[2]];
  const float* o_w = (const float*)d_in[widx[3]];
  float* out = (float*)d_out;

  const size_t elems = (size_t)BATCH * SEQ * DM;   // 8388608
  const size_t welems = (size_t)DM * DM;           // 1048576
  u16* Qb  = (u16*)d_ws;
  u16* Kb  = Qb + elems;
  u16* Vb  = Kb + elems;
  u16* AOb = Vb + elems;
  u16* xb  = AOb + elems;
  u16* qwb = xb + elems;
  u16* kwb = qwb + welems;
  u16* vwb = kwb + welems;
  u16* owb = vwb + welems;
  int* pmode = (int*)(owb + welems);   // ~92.3 MB into ws

  hipLaunchKernelGGL(possniff_kernel, dim3(1), dim3(1), 0, stream,
                     (const u32*)pos, pmode);

  // fp32 -> bf16 conversions
  hipLaunchKernelGGL(cvt_kernel, dim3(2048), dim3(256), 0, stream,
                     x, xb, (int)(elems / 4));
  hipLaunchKernelGGL(cvt_kernel, dim3(1024), dim3(256), 0, stream,
                     q_w, qwb, (int)(welems / 4));
  hipLaunchKernelGGL(cvt_kernel, dim3(1024), dim3(256), 0, stream,
                     k_w, kwb, (int)(welems / 4));
  hipLaunchKernelGGL(cvt_kernel, dim3(1024), dim3(256), 0, stream,
                     v_w, vwb, (int)(welems / 4));
  hipLaunchKernelGGL(cvt_kernel, dim3(1024), dim3(256), 0, stream,
                     o_w, owb, (int)(welems / 4));

  // Q/K/V projections (MFMA)
  dim3 ggrid(DM / 128, (BATCH * SEQ) / 128);  // (8, 64)
  gemm_mfma<1><<<ggrid, 256, 0, stream>>>(xb, qwb, nullptr, Qb);
  gemm_mfma<1><<<ggrid, 256, 0, stream>>>(xb, kwb, nullptr, Kb);
  gemm_mfma<1><<<ggrid, 256, 0, stream>>>(xb, vwb, nullptr, Vb);

  // RoPE (c9 convention)
  int rope_threads = BATCH * NH * SEQ * 32;
  hipLaunchKernelGGL(rope_c9, dim3(rope_threads / 256), dim3(256), 0, stream,
                     Qb, Kb, pos, pmode);

  // Attention
  hipLaunchKernelGGL(attn_naive, dim3(SEQ, BATCH * NH), dim3(256), 0, stream,
                     Qb, Kb, Vb, AOb);

  // O-projection -> fp32 out
  gemm_mfma<0><<<ggrid, 256, 0, stream>>>(AOb, owb, out, nullptr);
}

// Round 19
// 537.957 us; speedup vs baseline: 45.0529x; 8.9405x over previous
//
#include <hip/hip_runtime.h>
#include <math.h>

#define BATCH 4
#define SEQ 2048
#define DM 1024
#define NH 16
#define DH 64
#define LDK 72   // padded LDS row stride (u16): 144B, 16B-aligned, conflict-light

typedef unsigned int u32;
typedef unsigned short u16;
typedef __attribute__((ext_vector_type(8))) short bf16x8;
typedef __attribute__((ext_vector_type(8))) unsigned short u16x8;
typedef __attribute__((ext_vector_type(4))) float f32x4;

__device__ __forceinline__ float b2f(u16 h) {
  union { u32 u; float f; } v; v.u = ((u32)h) << 16; return v.f;
}
__device__ __forceinline__ u16 f2bf(float f) {
  union { u32 u; float f; } v; v.f = f;
  u32 lsb = (v.u >> 16) & 1u;
  v.u += 0x7FFFu + lsb;
  return (u16)(v.u >> 16);
}

__device__ __forceinline__ float read_pos(const void* p, int s, int mode) {
  if (mode == 1) return (float)(int)(((const unsigned long long*)p)[s]);
  if (mode == 2) return ((const float*)p)[s];
  return (float)(((const int*)p)[s]);
}

__global__ void possniff_kernel(const u32* __restrict__ pw, int* __restrict__ mode) {
  int m = 0;
  if (pw[1] == 1u && pw[2] == 2u && pw[3] == 3u) m = 0;
  else if (pw[2] == 1u && pw[4] == 2u && pw[6] == 3u) m = 1;
  else if (pw[1] == 0x3F800000u) m = 2;
  *mode = m;
}

// ============================================================
__global__ __launch_bounds__(256) void cvt_kernel(const float* __restrict__ in,
                                                  u16* __restrict__ out, int n4) {
  int i = blockIdx.x * 256 + threadIdx.x;
  int stride = gridDim.x * 256;
  for (; i < n4; i += stride) {
    float4 v = *(const float4*)(in + (size_t)i * 4);
    ushort4 o = make_ushort4(f2bf(v.x), f2bf(v.y), f2bf(v.z), f2bf(v.w));
    *(ushort4*)(out + (size_t)i * 4) = o;
  }
}

// ============================================================
// MFMA GEMM (unchanged from round 18, verified)
// ============================================================
template<int CMODE>
__global__ __launch_bounds__(256) void gemm_mfma(const u16* __restrict__ A,
                                                 const u16* __restrict__ W,
                                                 float* __restrict__ Cf,
                                                 u16* __restrict__ Cb) {
  __shared__ u16 As[128 * 32];
  __shared__ u16 Bs[128 * 32];
  const int tid = threadIdx.x;
  const int wave = tid >> 6;
  const int lane = tid & 63;
  const int wm = wave >> 1;
  const int wn = wave & 1;
  const int n0 = blockIdx.x * 128;
  const int m0 = blockIdx.y * 128;

  const int fl = lane & 15;
  const int kq = lane >> 4;
  const int s_r = lane >> 2;
  const int s_c = (lane & 3) * 8;

  const u16* Ag = A + (size_t)m0 * DM;
  const u16* Wg = W + (size_t)n0 * DM;

  f32x4 acc[4][4] = {};

  for (int k0 = 0; k0 < DM; k0 += 32) {
    __syncthreads();
#pragma unroll
    for (int j = 0; j < 2; ++j) {
      int row = wave * 32 + j * 16 + s_r;
      __builtin_amdgcn_global_load_lds(
          (const __attribute__((address_space(1))) void*)(Ag + (size_t)row * DM + k0 + s_c),
          (__attribute__((address_space(3))) void*)(As + wave * 1024 + j * 512),
          16, 0, 0);
      __builtin_amdgcn_global_load_lds(
          (const __attribute__((address_space(1))) void*)(Wg + (size_t)row * DM + k0 + s_c),
          (__attribute__((address_space(3))) void*)(Bs + wave * 1024 + j * 512),
          16, 0, 0);
    }
    __syncthreads();

    bf16x8 af[4], bfr[4];
#pragma unroll
    for (int m = 0; m < 4; ++m)
      af[m] = *(const bf16x8*)&As[(wm * 64 + m * 16 + fl) * 32 + kq * 8];
#pragma unroll
    for (int n = 0; n < 4; ++n)
      bfr[n] = *(const bf16x8*)&Bs[(wn * 64 + n * 16 + fl) * 32 + kq * 8];
#pragma unroll
    for (int m = 0; m < 4; ++m)
#pragma unroll
      for (int n = 0; n < 4; ++n)
        acc[m][n] = __builtin_amdgcn_mfma_f32_16x16x32_bf16(af[m], bfr[n],
                                                            acc[m][n], 0, 0, 0);
  }

#pragma unroll
  for (int m = 0; m < 4; ++m) {
#pragma unroll
    for (int n = 0; n < 4; ++n) {
      int gcol = n0 + wn * 64 + n * 16 + fl;
#pragma unroll
      for (int r = 0; r < 4; ++r) {
        int grow = m0 + wm * 64 + m * 16 + kq * 4 + r;
        float v = acc[m][n][r];
        if (CMODE == 0) {
          Cf[(size_t)grow * DM + gcol] = v;
        } else {
          int b = grow >> 11, s = grow & (SEQ - 1);
          int h = gcol >> 6, d = gcol & 63;
          Cb[((size_t)(b * NH + h) * SEQ + s) * DH + d] = f2bf(v);
        }
      }
    }
  }
}

// ============================================================
// RoPE c9 (unchanged)
// ============================================================
__global__ __launch_bounds__(256) void rope_c9(u16* __restrict__ Q,
                                               u16* __restrict__ K,
                                               const void* __restrict__ pos,
                                               const int* __restrict__ pmode) {
  int idx = blockIdx.x * blockDim.x + threadIdx.x;
  int i = idx & 31;
  int s = (idx >> 5) & (SEQ - 1);
  int bh = idx >> 16;
  float p = read_pos(pos, s, *pmode);
  float inv = powf(10000.0f, -(float)i * (1.0f / 32.0f));
  float ang = p * inv;
  float c, sn;
  sincosf(ang, &c, &sn);
  size_t base = ((size_t)bh * SEQ + s) * DH + 2 * i;
  float q1 = b2f(Q[base]), q2 = b2f(Q[base + 1]);
  Q[base]     = f2bf(q1 * c + q2 * sn);
  Q[base + 1] = f2bf(-q1 * sn + q2 * c);
  float k1 = b2f(K[base]), k2 = b2f(K[base + 1]);
  K[base]     = f2bf(k1 * c + k2 * sn);
  K[base + 1] = f2bf(-k1 * sn + k2 * c);
}

// ============================================================
// MFMA flash attention. Block = 4 waves, one (64-q-tile, bh).
// Wave w owns q-rows [w*16, w*16+16). QBLK=KVBLK=64.
// Fragment conventions identical to gemm_mfma (verified r18).
// ============================================================
__global__ __launch_bounds__(256) void attn_mfma(const u16* __restrict__ Q,
                                                 const u16* __restrict__ K,
                                                 const u16* __restrict__ V,
                                                 u16* __restrict__ AO) {
  __shared__ u16 Qs[64 * LDK];
  __shared__ u16 Ks[64 * LDK];
  __shared__ u16 Vt[64 * LDK];      // [d][kk]
  __shared__ u16 Ps[4][16 * LDK];   // per-wave P staging [q][kk]

  const int qt = 31 - blockIdx.x;   // heavy tiles first
  const int bh = blockIdx.y;
  const int tid = threadIdx.x;
  const int w = tid >> 6, lane = tid & 63;
  const int fl = lane & 15, kq = lane >> 4;
  const int q0 = qt * 64;
  const u16* Qg = Q + (size_t)bh * SEQ * DH;
  const u16* Kg = K + (size_t)bh * SEQ * DH;
  const u16* Vg = V + (size_t)bh * SEQ * DH;

  // ---- stage Q tile ----
#pragma unroll
  for (int rep = 0; rep < 2; ++rep) {
    int idx = rep * 256 + tid;         // 0..511
    int row = idx >> 3, oct = idx & 7;
    u16x8 v = *(const u16x8*)(Qg + (size_t)(q0 + row) * DH + oct * 8);
    *(u16x8*)&Qs[row * LDK + oct * 8] = v;
  }
  __syncthreads();

  bf16x8 aq0 = *(const bf16x8*)&Qs[(w * 16 + fl) * LDK + kq * 8];
  bf16x8 aq1 = *(const bf16x8*)&Qs[(w * 16 + fl) * LDK + 32 + kq * 8];

  f32x4 o_acc[4] = {};
  float m_i[4], l_i[4];
#pragma unroll
  for (int r = 0; r < 4; ++r) { m_i[r] = -INFINITY; l_i[r] = 0.f; }

  for (int kt = 0; kt <= qt; ++kt) {
    const int kb = kt * 64;
    __syncthreads();   // prior tile's Ks/Vt reads done
#pragma unroll
    for (int rep = 0; rep < 2; ++rep) {
      int idx = rep * 256 + tid;
      int row = idx >> 3, oct = idx & 7;
      u16x8 kv = *(const u16x8*)(Kg + (size_t)(kb + row) * DH + oct * 8);
      *(u16x8*)&Ks[row * LDK + oct * 8] = kv;
      u16x8 vv = *(const u16x8*)(Vg + (size_t)(kb + row) * DH + oct * 8);
#pragma unroll
      for (int j = 0; j < 8; ++j)
        Vt[(oct * 8 + j) * LDK + row] = (u16)vv[j];
    }
    __syncthreads();

    // ---- QK^T: S strip 16x64 ----
    f32x4 s_acc[4] = {};
#pragma unroll
    for (int n = 0; n < 4; ++n) {
      bf16x8 b0 = *(const bf16x8*)&Ks[(n * 16 + fl) * LDK + kq * 8];
      bf16x8 b1 = *(const bf16x8*)&Ks[(n * 16 + fl) * LDK + 32 + kq * 8];
      s_acc[n] = __builtin_amdgcn_mfma_f32_16x16x32_bf16(aq0, b0, s_acc[n], 0, 0, 0);
      s_acc[n] = __builtin_amdgcn_mfma_f32_16x16x32_bf16(aq1, b1, s_acc[n], 0, 0, 0);
    }

    // ---- scale + causal mask (diagonal tile only) ----
#pragma unroll
    for (int n = 0; n < 4; ++n)
#pragma unroll
      for (int r = 0; r < 4; ++r) {
        float s = s_acc[n][r] * 0.125f;
        if (kt == qt) {
          int qrow = w * 16 + kq * 4 + r;
          int kcol = n * 16 + fl;
          if (kcol > qrow) s = -3.0e38f;
        }
        s_acc[n][r] = s;
      }

    // ---- online softmax (per q-row; 16-lane groups share a row) ----
    float p[4][4];
#pragma unroll
    for (int r = 0; r < 4; ++r) {
      float mr = fmaxf(fmaxf(s_acc[0][r], s_acc[1][r]),
                       fmaxf(s_acc[2][r], s_acc[3][r]));
#pragma unroll
      for (int off = 1; off < 16; off <<= 1)
        mr = fmaxf(mr, __shfl_xor(mr, off, 64));
      float mnew = fmaxf(m_i[r], mr);
      float scf = expf(m_i[r] - mnew);   // first tile: exp(-inf)=0
      float rs = 0.f;
#pragma unroll
      for (int n = 0; n < 4; ++n) { p[n][r] = expf(s_acc[n][r] - mnew); rs += p[n][r]; }
#pragma unroll
      for (int off = 1; off < 16; off <<= 1)
        rs += __shfl_xor(rs, off, 64);
      l_i[r] = l_i[r] * scf + rs;
      m_i[r] = mnew;
#pragma unroll
      for (int n = 0; n < 4; ++n) o_acc[n][r] *= scf;
    }

    // ---- stage P (per-wave region, no cross-wave sync) ----
#pragma unroll
    for (int n = 0; n < 4; ++n)
#pragma unroll
      for (int r = 0; r < 4; ++r)
        Ps[w][(kq * 4 + r) * LDK + n * 16 + fl] = f2bf(p[n][r]);

    // ---- PV: O strip 16x64 += P(16x64) * V(64x64) ----
    bf16x8 ap0 = *(const bf16x8*)&Ps[w][fl * LDK + kq * 8];
    bf16x8 ap1 = *(const bf16x8*)&Ps[w][fl * LDK + 32 + kq * 8];
#pragma unroll
    for (int n = 0; n < 4; ++n) {
      bf16x8 b0 = *(const bf16x8*)&Vt[(n * 16 + fl) * LDK + kq * 8];
      bf16x8 b1 = *(const bf16x8*)&Vt[(n * 16 + fl) * LDK + 32 + kq * 8];
      o_acc[n] = __builtin_amdgcn_mfma_f32_16x16x32_bf16(ap0, b0, o_acc[n], 0, 0, 0);
      o_acc[n] = __builtin_amdgcn_mfma_f32_16x16x32_bf16(ap1, b1, o_acc[n], 0, 0, 0);
    }
  }

  // ---- epilogue: normalize + write [B,S,H*64] ----
  const int b = bh >> 4, h = bh & 15;
#pragma unroll
  for (int r = 0; r < 4; ++r) {
    float invl = 1.0f / l_i[r];
    int qrow = q0 + w * 16 + kq * 4 + r;
#pragma unroll
    for (int n = 0; n < 4; ++n) {
      int d = n * 16 + fl;
      AO[((size_t)(b * SEQ + qrow)) * DM + h * DH + d] = f2bf(o_acc[n][r] * invl);
    }
  }
}

// ============================================================
extern "C" void kernel_launch(void* const* d_in, const int* in_sizes, int n_in,
                              void* d_out, int out_size, void* d_ws, size_t ws_size,
                              hipStream_t stream) {
  int xi = -1, pi = -1, widx[8], nw = 0;
  for (int i = 0; i < n_in; ++i) {
    if (in_sizes[i] == BATCH * SEQ * DM) xi = i;
    else if (in_sizes[i] == SEQ) pi = i;
    else if (in_sizes[i] == DM * DM && nw < 8) widx[nw++] = i;
  }
  if (xi < 0) xi = 0;
  if (pi < 0) pi = 1;

  const float* x   = (const float*)d_in[xi];
  const void*  pos = d_in[pi];
  const float* q_w = (const float*)d_in[widx[0]];
  const float* k_w = (const float*)d_in[widx[1]];
  const float* v_w = (const float*)d_in[widx[2]];
  const float* o_w = (const float*)d_in[widx[3]];
  float* out = (float*)d_out;

  const size_t elems = (size_t)BATCH * SEQ * DM;   // 8388608
  const size_t welems = (size_t)DM * DM;           // 1048576
  u16* Qb  = (u16*)d_ws;
  u16* Kb  = Qb + elems;
  u16* Vb  = Kb + elems;
  u16* AOb = Vb + elems;
  u16* xb  = AOb + elems;
  u16* qwb = xb + elems;
  u16* kwb = qwb + welems;
  u16* vwb = kwb + welems;
  u16* owb = vwb + welems;
  int* pmode = (int*)(owb + welems);

  hipLaunchKernelGGL(possniff_kernel, dim3(1), dim3(1), 0, stream,
                     (const u32*)pos, pmode);

  hipLaunchKernelGGL(cvt_kernel, dim3(2048), dim3(256), 0, stream,
                     x, xb, (int)(elems / 4));
  hipLaunchKernelGGL(cvt_kernel, dim3(1024), dim3(256), 0, stream,
                     q_w, qwb, (int)(welems / 4));
  hipLaunchKernelGGL(cvt_kernel, dim3(1024), dim3(256), 0, stream,
                     k_w, kwb, (int)(welems / 4));
  hipLaunchKernelGGL(cvt_kernel, dim3(1024), dim3(256), 0, stream,
                     v_w, vwb, (int)(welems / 4));
  hipLaunchKernelGGL(cvt_kernel, dim3(1024), dim3(256), 0, stream,
                     o_w, owb, (int)(welems / 4));

  dim3 ggrid(DM / 128, (BATCH * SEQ) / 128);  // (8, 64)
  gemm_mfma<1><<<ggrid, 256, 0, stream>>>(xb, qwb, nullptr, Qb);
  gemm_mfma<1><<<ggrid, 256, 0, stream>>>(xb, kwb, nullptr, Kb);
  gemm_mfma<1><<<ggrid, 256, 0, stream>>>(xb, vwb, nullptr, Vb);

  int rope_threads = BATCH * NH * SEQ * 32;
  hipLaunchKernelGGL(rope_c9, dim3(rope_threads / 256), dim3(256), 0, stream,
                     Qb, Kb, pos, pmode);

  hipLaunchKernelGGL(attn_mfma, dim3(SEQ / 64, BATCH * NH), dim3(256), 0, stream,
                     Qb, Kb, Vb, AOb);

  gemm_mfma<0><<<ggrid, 256, 0, stream>>>(AOb, owb, out, nullptr);
}

// Round 20
// 518.064 us; speedup vs baseline: 46.7828x; 1.0384x over previous
//
#include <hip/hip_runtime.h>
#include <math.h>

#define BATCH 4
#define SEQ 2048
#define DM 1024
#define NH 16
#define DH 64
#define QBLK 128
#define KVBLK 64
#define LDP 72   // Ps padded row stride (u16)

typedef unsigned int u32;
typedef unsigned short u16;
typedef __attribute__((ext_vector_type(8))) short bf16x8;
typedef __attribute__((ext_vector_type(8))) unsigned short u16x8;
typedef __attribute__((ext_vector_type(4))) float f32x4;

__device__ __forceinline__ float b2f(u16 h) {
  union { u32 u; float f; } v; v.u = ((u32)h) << 16; return v.f;
}
__device__ __forceinline__ u16 f2bf(float f) {
  union { u32 u; float f; } v; v.f = f;
  u32 lsb = (v.u >> 16) & 1u;
  v.u += 0x7FFFu + lsb;
  return (u16)(v.u >> 16);
}

__device__ __forceinline__ float read_pos(const void* p, int s, int mode) {
  if (mode == 1) return (float)(int)(((const unsigned long long*)p)[s]);
  if (mode == 2) return ((const float*)p)[s];
  return (float)(((const int*)p)[s]);
}

__global__ void possniff_kernel(const u32* __restrict__ pw, int* __restrict__ mode) {
  int m = 0;
  if (pw[1] == 1u && pw[2] == 2u && pw[3] == 3u) m = 0;
  else if (pw[2] == 1u && pw[4] == 2u && pw[6] == 3u) m = 1;
  else if (pw[1] == 0x3F800000u) m = 2;
  *mode = m;
}

// ============================================================
__global__ __launch_bounds__(256) void cvt_kernel(const float* __restrict__ in,
                                                  u16* __restrict__ out, int n4) {
  int i = blockIdx.x * 256 + threadIdx.x;
  int stride = gridDim.x * 256;
  for (; i < n4; i += stride) {
    float4 v = *(const float4*)(in + (size_t)i * 4);
    ushort4 o = make_ushort4(f2bf(v.x), f2bf(v.y), f2bf(v.z), f2bf(v.w));
    *(ushort4*)(out + (size_t)i * 4) = o;
  }
}

// ============================================================
// MFMA GEMM (verified r18, unchanged)
// ============================================================
template<int CMODE>
__global__ __launch_bounds__(256) void gemm_mfma(const u16* __restrict__ A,
                                                 const u16* __restrict__ W,
                                                 float* __restrict__ Cf,
                                                 u16* __restrict__ Cb) {
  __shared__ u16 As[128 * 32];
  __shared__ u16 Bs[128 * 32];
  const int tid = threadIdx.x;
  const int wave = tid >> 6;
  const int lane = tid & 63;
  const int wm = wave >> 1;
  const int wn = wave & 1;
  const int n0 = blockIdx.x * 128;
  const int m0 = blockIdx.y * 128;

  const int fl = lane & 15;
  const int kq = lane >> 4;
  const int s_r = lane >> 2;
  const int s_c = (lane & 3) * 8;

  const u16* Ag = A + (size_t)m0 * DM;
  const u16* Wg = W + (size_t)n0 * DM;

  f32x4 acc[4][4] = {};

  for (int k0 = 0; k0 < DM; k0 += 32) {
    __syncthreads();
#pragma unroll
    for (int j = 0; j < 2; ++j) {
      int row = wave * 32 + j * 16 + s_r;
      __builtin_amdgcn_global_load_lds(
          (const __attribute__((address_space(1))) void*)(Ag + (size_t)row * DM + k0 + s_c),
          (__attribute__((address_space(3))) void*)(As + wave * 1024 + j * 512),
          16, 0, 0);
      __builtin_amdgcn_global_load_lds(
          (const __attribute__((address_space(1))) void*)(Wg + (size_t)row * DM + k0 + s_c),
          (__attribute__((address_space(3))) void*)(Bs + wave * 1024 + j * 512),
          16, 0, 0);
    }
    __syncthreads();

    bf16x8 af[4], bfr[4];
#pragma unroll
    for (int m = 0; m < 4; ++m)
      af[m] = *(const bf16x8*)&As[(wm * 64 + m * 16 + fl) * 32 + kq * 8];
#pragma unroll
    for (int n = 0; n < 4; ++n)
      bfr[n] = *(const bf16x8*)&Bs[(wn * 64 + n * 16 + fl) * 32 + kq * 8];
#pragma unroll
    for (int m = 0; m < 4; ++m)
#pragma unroll
      for (int n = 0; n < 4; ++n)
        acc[m][n] = __builtin_amdgcn_mfma_f32_16x16x32_bf16(af[m], bfr[n],
                                                            acc[m][n], 0, 0, 0);
  }

#pragma unroll
  for (int m = 0; m < 4; ++m) {
#pragma unroll
    for (int n = 0; n < 4; ++n) {
      int gcol = n0 + wn * 64 + n * 16 + fl;
#pragma unroll
      for (int r = 0; r < 4; ++r) {
        int grow = m0 + wm * 64 + m * 16 + kq * 4 + r;
        float v = acc[m][n][r];
        if (CMODE == 0) {
          Cf[(size_t)grow * DM + gcol] = v;
        } else {
          int b = grow >> 11, s = grow & (SEQ - 1);
          int h = gcol >> 6, d = gcol & 63;
          Cb[((size_t)(b * NH + h) * SEQ + s) * DH + d] = f2bf(v);
        }
      }
    }
  }
}

// ============================================================
// RoPE c9 (unchanged)
// ============================================================
__global__ __launch_bounds__(256) void rope_c9(u16* __restrict__ Q,
                                               u16* __restrict__ K,
                                               const void* __restrict__ pos,
                                               const int* __restrict__ pmode) {
  int idx = blockIdx.x * blockDim.x + threadIdx.x;
  int i = idx & 31;
  int s = (idx >> 5) & (SEQ - 1);
  int bh = idx >> 16;
  float p = read_pos(pos, s, *pmode);
  float inv = powf(10000.0f, -(float)i * (1.0f / 32.0f));
  float ang = p * inv;
  float c, sn;
  sincosf(ang, &c, &sn);
  size_t base = ((size_t)bh * SEQ + s) * DH + 2 * i;
  float q1 = b2f(Q[base]), q2 = b2f(Q[base + 1]);
  Q[base]     = f2bf(q1 * c + q2 * sn);
  Q[base + 1] = f2bf(-q1 * sn + q2 * c);
  float k1 = b2f(K[base]), k2 = b2f(K[base + 1]);
  K[base]     = f2bf(k1 * c + k2 * sn);
  K[base + 1] = f2bf(-k1 * sn + k2 * c);
}

// ============================================================
// MFMA flash attention v2: QBLK=128 (wave owns 32 q-rows in two
// 16-row halves), KVBLK=64, XOR-swizzled linear LDS (no pad) for
// Q/K/Vt, padded Ps. Swizzles:
//   Qs/Ks: slot_oct = oct ^ (row&7); read oct' = (kq+4c) ^ (fl&7)
//   Vt: slot kk' = kk ^ (((oct_d ^ j)&7)<<3); read oct' = (kq+4c) ^ cv,
//       cv = ((d>>3) ^ (d&7)) & 7
// ============================================================
__global__ __launch_bounds__(256) void attn_mfma(const u16* __restrict__ Q,
                                                 const u16* __restrict__ K,
                                                 const u16* __restrict__ V,
                                                 u16* __restrict__ AO) {
  __shared__ u16 Qs[QBLK * 64];
  __shared__ u16 Ks[KVBLK * 64];
  __shared__ u16 Vt[64 * KVBLK];
  __shared__ u16 Ps[4][16 * LDP];

  const int qt = (SEQ / QBLK - 1) - blockIdx.x;   // heavy first
  const int bh = blockIdx.y;
  const int tid = threadIdx.x;
  const int w = tid >> 6, lane = tid & 63;
  const int fl = lane & 15, kq = lane >> 4;
  const int q0 = qt * QBLK;
  const u16* Qg = Q + (size_t)bh * SEQ * DH;
  const u16* Kg = K + (size_t)bh * SEQ * DH;
  const u16* Vg = V + (size_t)bh * SEQ * DH;

  // ---- stage Q tile (128 rows), swizzled ----
#pragma unroll
  for (int rep = 0; rep < 4; ++rep) {
    int idx = rep * 256 + tid;        // 0..1023
    int row = idx >> 3, oct = idx & 7;
    u16x8 v = *(const u16x8*)(Qg + (size_t)(q0 + row) * DH + oct * 8);
    *(u16x8*)&Qs[row * 64 + ((oct ^ (row & 7)) * 8)] = v;
  }
  __syncthreads();

  bf16x8 aq[2][2];
#pragma unroll
  for (int m = 0; m < 2; ++m) {
    int qrow = w * 32 + m * 16 + fl;
#pragma unroll
    for (int c = 0; c < 2; ++c)
      aq[m][c] = *(const bf16x8*)&Qs[qrow * 64 + (((kq + 4 * c) ^ (fl & 7)) * 8)];
  }

  f32x4 o_acc[2][4] = {};
  float m_i[2][4], l_i[2][4];
#pragma unroll
  for (int m = 0; m < 2; ++m)
#pragma unroll
    for (int r = 0; r < 4; ++r) { m_i[m][r] = -INFINITY; l_i[m][r] = 0.f; }

  const int ktmax = 2 * qt + 1;
  for (int kt = 0; kt <= ktmax; ++kt) {
    const int kb = kt * KVBLK;
    __syncthreads();
#pragma unroll
    for (int rep = 0; rep < 2; ++rep) {
      int idx = rep * 256 + tid;
      int row = idx >> 3, oct = idx & 7;
      u16x8 kv = *(const u16x8*)(Kg + (size_t)(kb + row) * DH + oct * 8);
      *(u16x8*)&Ks[row * 64 + ((oct ^ (row & 7)) * 8)] = kv;
      u16x8 vv = *(const u16x8*)(Vg + (size_t)(kb + row) * DH + oct * 8);
#pragma unroll
      for (int j = 0; j < 8; ++j) {
        int d = oct * 8 + j;
        Vt[d * 64 + (row ^ (((oct ^ j) & 7) << 3))] = (u16)vv[j];
      }
    }
    __syncthreads();

#pragma unroll
    for (int m = 0; m < 2; ++m) {
      const int qbase = q0 + w * 32 + m * 16;   // global first q-row of half
      if (kb > qbase + 15) continue;            // fully masked
      const bool need_mask = (kb + KVBLK - 1 > qbase);

      // ---- QK^T: 16 x 64 strip ----
      f32x4 s_acc[4] = {};
#pragma unroll
      for (int n = 0; n < 4; ++n) {
        bf16x8 b0 = *(const bf16x8*)&Ks[(n * 16 + fl) * 64 + ((kq ^ (fl & 7)) * 8)];
        bf16x8 b1 = *(const bf16x8*)&Ks[(n * 16 + fl) * 64 + (((kq + 4) ^ (fl & 7)) * 8)];
        s_acc[n] = __builtin_amdgcn_mfma_f32_16x16x32_bf16(aq[m][0], b0, s_acc[n], 0, 0, 0);
        s_acc[n] = __builtin_amdgcn_mfma_f32_16x16x32_bf16(aq[m][1], b1, s_acc[n], 0, 0, 0);
      }

#pragma unroll
      for (int n = 0; n < 4; ++n)
#pragma unroll
        for (int r = 0; r < 4; ++r) {
          float s = s_acc[n][r] * 0.125f;
          if (need_mask) {
            int qrow = qbase + kq * 4 + r;
            int kcol = kb + n * 16 + fl;
            if (kcol > qrow) s = -3.0e38f;
          }
          s_acc[n][r] = s;
        }

      // ---- online softmax ----
      float p[4][4];
#pragma unroll
      for (int r = 0; r < 4; ++r) {
        float mr = fmaxf(fmaxf(s_acc[0][r], s_acc[1][r]),
                         fmaxf(s_acc[2][r], s_acc[3][r]));
#pragma unroll
        for (int off = 1; off < 16; off <<= 1)
          mr = fmaxf(mr, __shfl_xor(mr, off, 64));
        float mnew = fmaxf(m_i[m][r], mr);
        float scf = expf(m_i[m][r] - mnew);
        float rs = 0.f;
#pragma unroll
        for (int n = 0; n < 4; ++n) { p[n][r] = expf(s_acc[n][r] - mnew); rs += p[n][r]; }
#pragma unroll
        for (int off = 1; off < 16; off <<= 1)
          rs += __shfl_xor(rs, off, 64);
        l_i[m][r] = l_i[m][r] * scf + rs;
        m_i[m][r] = mnew;
#pragma unroll
        for (int n = 0; n < 4; ++n) o_acc[m][n][r] *= scf;
      }

      // ---- stage P (per-wave, padded) ----
#pragma unroll
      for (int n = 0; n < 4; ++n)
#pragma unroll
        for (int r = 0; r < 4; ++r)
          Ps[w][(kq * 4 + r) * LDP + n * 16 + fl] = f2bf(p[n][r]);

      // ---- PV ----
      bf16x8 ap0 = *(const bf16x8*)&Ps[w][fl * LDP + kq * 8];
      bf16x8 ap1 = *(const bf16x8*)&Ps[w][fl * LDP + 32 + kq * 8];
#pragma unroll
      for (int n = 0; n < 4; ++n) {
        int d = n * 16 + fl;
        int cv = (((d >> 3) ^ d) & 7);
        bf16x8 b0 = *(const bf16x8*)&Vt[d * 64 + ((kq ^ cv) * 8)];
        bf16x8 b1 = *(const bf16x8*)&Vt[d * 64 + (((kq + 4) ^ cv) * 8)];
        o_acc[m][n] = __builtin_amdgcn_mfma_f32_16x16x32_bf16(ap0, b0, o_acc[m][n], 0, 0, 0);
        o_acc[m][n] = __builtin_amdgcn_mfma_f32_16x16x32_bf16(ap1, b1, o_acc[m][n], 0, 0, 0);
      }
    }
  }

  // ---- epilogue ----
  const int b = bh >> 4, h = bh & 15;
#pragma unroll
  for (int m = 0; m < 2; ++m)
#pragma unroll
    for (int r = 0; r < 4; ++r) {
      float invl = 1.0f / l_i[m][r];
      int qrow = q0 + w * 32 + m * 16 + kq * 4 + r;
#pragma unroll
      for (int n = 0; n < 4; ++n) {
        int d = n * 16 + fl;
        AO[((size_t)(b * SEQ + qrow)) * DM + h * DH + d] = f2bf(o_acc[m][n][r] * invl);
      }
    }
}

// ============================================================
extern "C" void kernel_launch(void* const* d_in, const int* in_sizes, int n_in,
                              void* d_out, int out_size, void* d_ws, size_t ws_size,
                              hipStream_t stream) {
  int xi = -1, pi = -1, widx[8], nw = 0;
  for (int i = 0; i < n_in; ++i) {
    if (in_sizes[i] == BATCH * SEQ * DM) xi = i;
    else if (in_sizes[i] == SEQ) pi = i;
    else if (in_sizes[i] == DM * DM && nw < 8) widx[nw++] = i;
  }
  if (xi < 0) xi = 0;
  if (pi < 0) pi = 1;

  const float* x   = (const float*)d_in[xi];
  const void*  pos = d_in[pi];
  const float* q_w = (const float*)d_in[widx[0]];
  const float* k_w = (const float*)d_in[widx[1]];
  const float* v_w = (const float*)d_in[widx[2]];
  const float* o_w = (const float*)d_in[widx[3]];
  float* out = (float*)d_out;

  const size_t elems = (size_t)BATCH * SEQ * DM;   // 8388608
  const size_t welems = (size_t)DM * DM;           // 1048576
  u16* Qb  = (u16*)d_ws;
  u16* Kb  = Qb + elems;
  u16* Vb  = Kb + elems;
  u16* AOb = Vb + elems;
  u16* xb  = AOb + elems;
  u16* qwb = xb + elems;
  u16* kwb = qwb + welems;
  u16* vwb = kwb + welems;
  u16* owb = vwb + welems;
  int* pmode = (int*)(owb + welems);

  hipLaunchKernelGGL(possniff_kernel, dim3(1), dim3(1), 0, stream,
                     (const u32*)pos, pmode);

  hipLaunchKernelGGL(cvt_kernel, dim3(2048), dim3(256), 0, stream,
                     x, xb, (int)(elems / 4));
  hipLaunchKernelGGL(cvt_kernel, dim3(1024), dim3(256), 0, stream,
                     q_w, qwb, (int)(welems / 4));
  hipLaunchKernelGGL(cvt_kernel, dim3(1024), dim3(256), 0, stream,
                     k_w, kwb, (int)(welems / 4));
  hipLaunchKernelGGL(cvt_kernel, dim3(1024), dim3(256), 0, stream,
                     v_w, vwb, (int)(welems / 4));
  hipLaunchKernelGGL(cvt_kernel, dim3(1024), dim3(256), 0, stream,
                     o_w, owb, (int)(welems / 4));

  dim3 ggrid(DM / 128, (BATCH * SEQ) / 128);  // (8, 64)
  gemm_mfma<1><<<ggrid, 256, 0, stream>>>(xb, qwb, nullptr, Qb);
  gemm_mfma<1><<<ggrid, 256, 0, stream>>>(xb, kwb, nullptr, Kb);
  gemm_mfma<1><<<ggrid, 256, 0, stream>>>(xb, vwb, nullptr, Vb);

  int rope_threads = BATCH * NH * SEQ * 32;
  hipLaunchKernelGGL(rope_c9, dim3(rope_threads / 256), dim3(256), 0, stream,
                     Qb, Kb, pos, pmode);

  hipLaunchKernelGGL(attn_mfma, dim3(SEQ / QBLK, BATCH * NH), dim3(256), 0, stream,
                     Qb, Kb, Vb, AOb);

  gemm_mfma<0><<<ggrid, 256, 0, stream>>>(AOb, owb, out, nullptr);
}

// Round 21
// 366.369 us; speedup vs baseline: 66.1532x; 1.4140x over previous
//
#include <hip/hip_runtime.h>
#include <math.h>

#define BATCH 4
#define SEQ 2048
#define DM 1024
#define NH 16
#define DH 64
#define QBLK 128
#define KVBLK 64

typedef unsigned int u32;
typedef unsigned short u16;
typedef __attribute__((ext_vector_type(8))) short bf16x8;
typedef __attribute__((ext_vector_type(8))) unsigned short u16x8;
typedef __attribute__((ext_vector_type(4))) float f32x4;

__device__ __forceinline__ float b2f(u16 h) {
  union { u32 u; float f; } v; v.u = ((u32)h) << 16; return v.f;
}
__device__ __forceinline__ u16 f2bf(float f) {
  union { u32 u; float f; } v; v.f = f;
  u32 lsb = (v.u >> 16) & 1u;
  v.u += 0x7FFFu + lsb;
  return (u16)(v.u >> 16);
}

__device__ __forceinline__ float read_pos(const void* p, int s, int mode) {
  if (mode == 1) return (float)(int)(((const unsigned long long*)p)[s]);
  if (mode == 2) return ((const float*)p)[s];
  return (float)(((const int*)p)[s]);
}

__global__ void possniff_kernel(const u32* __restrict__ pw, int* __restrict__ mode) {
  int m = 0;
  if (pw[1] == 1u && pw[2] == 2u && pw[3] == 3u) m = 0;
  else if (pw[2] == 1u && pw[4] == 2u && pw[6] == 3u) m = 1;
  else if (pw[1] == 0x3F800000u) m = 2;
  *mode = m;
}

// ============================================================
__global__ __launch_bounds__(256) void cvt_kernel(const float* __restrict__ in,
                                                  u16* __restrict__ out, int n4) {
  int i = blockIdx.x * 256 + threadIdx.x;
  int stride = gridDim.x * 256;
  for (; i < n4; i += stride) {
    float4 v = *(const float4*)(in + (size_t)i * 4);
    ushort4 o = make_ushort4(f2bf(v.x), f2bf(v.y), f2bf(v.z), f2bf(v.w));
    *(ushort4*)(out + (size_t)i * 4) = o;
  }
}

// ============================================================
// MFMA GEMM (verified r18). CMODE: 0 = fp32 C[m*1024+n],
// 1 = bf16 QKV [B,H,S,64], 2 = bf16 V-transposed [B,H,64,S]
// ============================================================
template<int CMODE>
__global__ __launch_bounds__(256) void gemm_mfma(const u16* __restrict__ A,
                                                 const u16* __restrict__ W,
                                                 float* __restrict__ Cf,
                                                 u16* __restrict__ Cb) {
  __shared__ u16 As[128 * 32];
  __shared__ u16 Bs[128 * 32];
  const int tid = threadIdx.x;
  const int wave = tid >> 6;
  const int lane = tid & 63;
  const int wm = wave >> 1;
  const int wn = wave & 1;
  const int n0 = blockIdx.x * 128;
  const int m0 = blockIdx.y * 128;

  const int fl = lane & 15;
  const int kq = lane >> 4;
  const int s_r = lane >> 2;
  const int s_c = (lane & 3) * 8;

  const u16* Ag = A + (size_t)m0 * DM;
  const u16* Wg = W + (size_t)n0 * DM;

  f32x4 acc[4][4] = {};

  for (int k0 = 0; k0 < DM; k0 += 32) {
    __syncthreads();
#pragma unroll
    for (int j = 0; j < 2; ++j) {
      int row = wave * 32 + j * 16 + s_r;
      __builtin_amdgcn_global_load_lds(
          (const __attribute__((address_space(1))) void*)(Ag + (size_t)row * DM + k0 + s_c),
          (__attribute__((address_space(3))) void*)(As + wave * 1024 + j * 512),
          16, 0, 0);
      __builtin_amdgcn_global_load_lds(
          (const __attribute__((address_space(1))) void*)(Wg + (size_t)row * DM + k0 + s_c),
          (__attribute__((address_space(3))) void*)(Bs + wave * 1024 + j * 512),
          16, 0, 0);
    }
    __syncthreads();

    bf16x8 af[4], bfr[4];
#pragma unroll
    for (int m = 0; m < 4; ++m)
      af[m] = *(const bf16x8*)&As[(wm * 64 + m * 16 + fl) * 32 + kq * 8];
#pragma unroll
    for (int n = 0; n < 4; ++n)
      bfr[n] = *(const bf16x8*)&Bs[(wn * 64 + n * 16 + fl) * 32 + kq * 8];
#pragma unroll
    for (int m = 0; m < 4; ++m)
#pragma unroll
      for (int n = 0; n < 4; ++n)
        acc[m][n] = __builtin_amdgcn_mfma_f32_16x16x32_bf16(af[m], bfr[n],
                                                            acc[m][n], 0, 0, 0);
  }

#pragma unroll
  for (int m = 0; m < 4; ++m) {
#pragma unroll
    for (int n = 0; n < 4; ++n) {
      int gcol = n0 + wn * 64 + n * 16 + fl;
#pragma unroll
      for (int r = 0; r < 4; ++r) {
        int grow = m0 + wm * 64 + m * 16 + kq * 4 + r;
        float v = acc[m][n][r];
        if (CMODE == 0) {
          Cf[(size_t)grow * DM + gcol] = v;
        } else if (CMODE == 1) {
          int b = grow >> 11, s = grow & (SEQ - 1);
          int h = gcol >> 6, d = gcol & 63;
          Cb[((size_t)(b * NH + h) * SEQ + s) * DH + d] = f2bf(v);
        } else {
          int b = grow >> 11, s = grow & (SEQ - 1);
          int h = gcol >> 6, d = gcol & 63;
          Cb[((size_t)(b * NH + h) * DH + d) * SEQ + s] = f2bf(v);
        }
      }
    }
  }
}

// ============================================================
// RoPE c9 (unchanged)
// ============================================================
__global__ __launch_bounds__(256) void rope_c9(u16* __restrict__ Q,
                                               u16* __restrict__ K,
                                               const void* __restrict__ pos,
                                               const int* __restrict__ pmode) {
  int idx = blockIdx.x * blockDim.x + threadIdx.x;
  int i = idx & 31;
  int s = (idx >> 5) & (SEQ - 1);
  int bh = idx >> 16;
  float p = read_pos(pos, s, *pmode);
  float inv = powf(10000.0f, -(float)i * (1.0f / 32.0f));
  float ang = p * inv;
  float c, sn;
  sincosf(ang, &c, &sn);
  size_t base = ((size_t)bh * SEQ + s) * DH + 2 * i;
  float q1 = b2f(Q[base]), q2 = b2f(Q[base + 1]);
  Q[base]     = f2bf(q1 * c + q2 * sn);
  Q[base + 1] = f2bf(-q1 * sn + q2 * c);
  float k1 = b2f(K[base]), k2 = b2f(K[base + 1]);
  K[base]     = f2bf(k1 * c + k2 * sn);
  K[base + 1] = f2bf(-k1 * sn + k2 * c);
}

// ============================================================
// MFMA flash attention v3:
//  - fixed-max softmax (M=14): p = exp2(s*log2e/8 - M*log2e); the 2^-M
//    cancels in O = (P V)/l. No shuffles, no rescale.
//  - l via ones-fragment MFMA (row sums land in acc like o_acc rows).
//  - V pre-transposed in global [B,H,D,S]: staging = vectorized like K.
//  - Ps overlays Qs (dead after fragment load): LDS 32KB -> 5 blocks/CU.
//  - K/V B-fragments shared across both q-halves: 20 ds_read_b128/tile.
// ============================================================
__global__ __launch_bounds__(256) void attn_mfma(const u16* __restrict__ Q,
                                                 const u16* __restrict__ K,
                                                 const u16* __restrict__ Vt_g,
                                                 u16* __restrict__ AO) {
  __shared__ u16 Qs[QBLK * 64];     // Ps overlay after fragment load
  __shared__ u16 Ks[KVBLK * 64];
  __shared__ u16 Vs[64 * KVBLK];    // V^T tile [d][kk]

  const int qt = (SEQ / QBLK - 1) - blockIdx.x;   // heavy first
  const int bh = blockIdx.y;
  const int tid = threadIdx.x;
  const int w = tid >> 6, lane = tid & 63;
  const int fl = lane & 15, kq = lane >> 4;
  const int fl7 = fl & 7;
  const int q0 = qt * QBLK;
  const u16* Qg = Q + (size_t)bh * SEQ * DH;
  const u16* Kg = K + (size_t)bh * SEQ * DH;
  const u16* Vg = Vt_g + (size_t)bh * DH * SEQ;

  // ---- stage Q tile (swizzled) ----
#pragma unroll
  for (int rep = 0; rep < 4; ++rep) {
    int idx = rep * 256 + tid;
    int row = idx >> 3, oct = idx & 7;
    u16x8 v = *(const u16x8*)(Qg + (size_t)(q0 + row) * DH + oct * 8);
    *(u16x8*)&Qs[row * 64 + ((oct ^ (row & 7)) * 8)] = v;
  }
  __syncthreads();

  bf16x8 aq[2][2];
#pragma unroll
  for (int m = 0; m < 2; ++m) {
    int qrow = w * 32 + m * 16 + fl;
#pragma unroll
    for (int c = 0; c < 2; ++c)
      aq[m][c] = *(const bf16x8*)&Qs[qrow * 64 + (((kq + 4 * c) ^ fl7) * 8)];
  }

  u16* Ps = Qs;   // overlay: row rr = w*32 + m*16 + kq*4+r  (128 rows x 64)

  const short ONE = 0x3F80;
  const bf16x8 ones = {ONE, ONE, ONE, ONE, ONE, ONE, ONE, ONE};
  const float C1 = 0.125f * 1.4426950408889634f;
  const float C2 = 14.0f * 1.4426950408889634f;

  f32x4 o_acc[2][4] = {};
  f32x4 l_acc[2] = {};

  const int ktmax = 2 * qt + 1;
  for (int kt = 0; kt <= ktmax; ++kt) {
    const int kb = kt * KVBLK;
    __syncthreads();
#pragma unroll
    for (int rep = 0; rep < 2; ++rep) {
      int idx = rep * 256 + tid;
      int row = idx >> 3, oct = idx & 7;
      u16x8 kv = *(const u16x8*)(Kg + (size_t)(kb + row) * DH + oct * 8);
      *(u16x8*)&Ks[row * 64 + ((oct ^ (row & 7)) * 8)] = kv;
      u16x8 vv = *(const u16x8*)(Vg + (size_t)row * SEQ + kb + oct * 8);
      *(u16x8*)&Vs[row * 64 + ((oct ^ (row & 7)) * 8)] = vv;
    }
    __syncthreads();

    const int qb0 = q0 + w * 32;
    const bool act0 = (kb <= qb0 + 15);
    const bool act1 = (kb <= qb0 + 31);
    if (!act1) continue;

    // ---- QK^T (shared K fragments) ----
    f32x4 s0[4] = {}, s1[4] = {};
#pragma unroll
    for (int n = 0; n < 4; ++n) {
      int row = n * 16 + fl;
      bf16x8 b0 = *(const bf16x8*)&Ks[row * 64 + ((kq ^ fl7) * 8)];
      bf16x8 b1 = *(const bf16x8*)&Ks[row * 64 + (((kq + 4) ^ fl7) * 8)];
      if (act0) {
        s0[n] = __builtin_amdgcn_mfma_f32_16x16x32_bf16(aq[0][0], b0, s0[n], 0, 0, 0);
        s0[n] = __builtin_amdgcn_mfma_f32_16x16x32_bf16(aq[0][1], b1, s0[n], 0, 0, 0);
      }
      s1[n] = __builtin_amdgcn_mfma_f32_16x16x32_bf16(aq[1][0], b0, s1[n], 0, 0, 0);
      s1[n] = __builtin_amdgcn_mfma_f32_16x16x32_bf16(aq[1][1], b1, s1[n], 0, 0, 0);
    }

    // ---- fixed-max softmax + stage P (both halves) ----
#pragma unroll
    for (int m = 0; m < 2; ++m) {
      if (m == 0 && !act0) continue;
      const int qbm = qb0 + m * 16;
      const bool nm = (kb + KVBLK - 1 > qbm);
#pragma unroll
      for (int n = 0; n < 4; ++n)
#pragma unroll
        for (int r = 0; r < 4; ++r) {
          float sv = (m == 0) ? s0[n][r] : s1[n][r];
          float p;
          if (nm) {
            int qrow = qbm + kq * 4 + r;
            int kcol = kb + n * 16 + fl;
            p = (kcol > qrow) ? 0.f : exp2f(sv * C1 - C2);
          } else {
            p = exp2f(sv * C1 - C2);
          }
          int rr = w * 32 + m * 16 + kq * 4 + r;
          Ps[rr * 64 + ((((n * 2 + (fl >> 3)) ^ (rr & 7)) << 3) | fl7)] = f2bf(p);
        }
    }

    // ---- P fragments ----
    bf16x8 ap[2][2];
#pragma unroll
    for (int m = 0; m < 2; ++m) {
      int ar = w * 32 + m * 16 + fl;
      ap[m][0] = *(const bf16x8*)&Ps[ar * 64 + ((kq ^ fl7) * 8)];
      ap[m][1] = *(const bf16x8*)&Ps[ar * 64 + (((kq + 4) ^ fl7) * 8)];
    }

    // ---- PV (shared V fragments) + denominators ----
#pragma unroll
    for (int n = 0; n < 4; ++n) {
      int row = n * 16 + fl;
      bf16x8 vb0 = *(const bf16x8*)&Vs[row * 64 + ((kq ^ fl7) * 8)];
      bf16x8 vb1 = *(const bf16x8*)&Vs[row * 64 + (((kq + 4) ^ fl7) * 8)];
      if (act0) {
        o_acc[0][n] = __builtin_amdgcn_mfma_f32_16x16x32_bf16(ap[0][0], vb0, o_acc[0][n], 0, 0, 0);
        o_acc[0][n] = __builtin_amdgcn_mfma_f32_16x16x32_bf16(ap[0][1], vb1, o_acc[0][n], 0, 0, 0);
      }
      o_acc[1][n] = __builtin_amdgcn_mfma_f32_16x16x32_bf16(ap[1][0], vb0, o_acc[1][n], 0, 0, 0);
      o_acc[1][n] = __builtin_amdgcn_mfma_f32_16x16x32_bf16(ap[1][1], vb1, o_acc[1][n], 0, 0, 0);
    }
    if (act0) {
      l_acc[0] = __builtin_amdgcn_mfma_f32_16x16x32_bf16(ap[0][0], ones, l_acc[0], 0, 0, 0);
      l_acc[0] = __builtin_amdgcn_mfma_f32_16x16x32_bf16(ap[0][1], ones, l_acc[0], 0, 0, 0);
    }
    l_acc[1] = __builtin_amdgcn_mfma_f32_16x16x32_bf16(ap[1][0], ones, l_acc[1], 0, 0, 0);
    l_acc[1] = __builtin_amdgcn_mfma_f32_16x16x32_bf16(ap[1][1], ones, l_acc[1], 0, 0, 0);
  }

  // ---- epilogue ----
  const int b = bh >> 4, h = bh & 15;
#pragma unroll
  for (int m = 0; m < 2; ++m)
#pragma unroll
    for (int r = 0; r < 4; ++r) {
      float invl = 1.0f / l_acc[m][r];
      int qrow = q0 + w * 32 + m * 16 + kq * 4 + r;
#pragma unroll
      for (int n = 0; n < 4; ++n) {
        int d = n * 16 + fl;
        AO[((size_t)(b * SEQ + qrow)) * DM + h * DH + d] = f2bf(o_acc[m][n][r] * invl);
      }
    }
}

// ============================================================
extern "C" void kernel_launch(void* const* d_in, const int* in_sizes, int n_in,
                              void* d_out, int out_size, void* d_ws, size_t ws_size,
                              hipStream_t stream) {
  int xi = -1, pi = -1, widx[8], nw = 0;
  for (int i = 0; i < n_in; ++i) {
    if (in_sizes[i] == BATCH * SEQ * DM) xi = i;
    else if (in_sizes[i] == SEQ) pi = i;
    else if (in_sizes[i] == DM * DM && nw < 8) widx[nw++] = i;
  }
  if (xi < 0) xi = 0;
  if (pi < 0) pi = 1;

  const float* x   = (const float*)d_in[xi];
  const void*  pos = d_in[pi];
  const float* q_w = (const float*)d_in[widx[0]];
  const float* k_w = (const float*)d_in[widx[1]];
  const float* v_w = (const float*)d_in[widx[2]];
  const float* o_w = (const float*)d_in[widx[3]];
  float* out = (float*)d_out;

  const size_t elems = (size_t)BATCH * SEQ * DM;   // 8388608
  const size_t welems = (size_t)DM * DM;           // 1048576
  u16* Qb  = (u16*)d_ws;
  u16* Kb  = Qb + elems;
  u16* Vtb = Kb + elems;   // [B,H,D,S]
  u16* AOb = Vtb + elems;
  u16* xb  = AOb + elems;
  u16* qwb = xb + elems;
  u16* kwb = qwb + welems;
  u16* vwb = kwb + welems;
  u16* owb = vwb + welems;
  int* pmode = (int*)(owb + welems);

  hipLaunchKernelGGL(possniff_kernel, dim3(1), dim3(1), 0, stream,
                     (const u32*)pos, pmode);

  hipLaunchKernelGGL(cvt_kernel, dim3(2048), dim3(256), 0, stream,
                     x, xb, (int)(elems / 4));
  hipLaunchKernelGGL(cvt_kernel, dim3(1024), dim3(256), 0, stream,
                     q_w, qwb, (int)(welems / 4));
  hipLaunchKernelGGL(cvt_kernel, dim3(1024), dim3(256), 0, stream,
                     k_w, kwb, (int)(welems / 4));
  hipLaunchKernelGGL(cvt_kernel, dim3(1024), dim3(256), 0, stream,
                     v_w, vwb, (int)(welems / 4));
  hipLaunchKernelGGL(cvt_kernel, dim3(1024), dim3(256), 0, stream,
                     o_w, owb, (int)(welems / 4));

  dim3 ggrid(DM / 128, (BATCH * SEQ) / 128);  // (8, 64)
  gemm_mfma<1><<<ggrid, 256, 0, stream>>>(xb, qwb, nullptr, Qb);
  gemm_mfma<1><<<ggrid, 256, 0, stream>>>(xb, kwb, nullptr, Kb);
  gemm_mfma<2><<<ggrid, 256, 0, stream>>>(xb, vwb, nullptr, Vtb);

  int rope_threads = BATCH * NH * SEQ * 32;
  hipLaunchKernelGGL(rope_c9, dim3(rope_threads / 256), dim3(256), 0, stream,
                     Qb, Kb, pos, pmode);

  hipLaunchKernelGGL(attn_mfma, dim3(SEQ / QBLK, BATCH * NH), dim3(256), 0, stream,
                     Qb, Kb, Vtb, AOb);

  gemm_mfma<0><<<ggrid, 256, 0, stream>>>(AOb, owb, out, nullptr);
}

// Round 22
// 281.624 us; speedup vs baseline: 86.0598x; 1.3009x over previous
//
#include <hip/hip_runtime.h>
#include <math.h>

#define BATCH 4
#define SEQ 2048
#define DM 1024
#define NH 16
#define DH 64
#define QBLK 128
#define KVBLK 128

typedef unsigned int u32;
typedef unsigned short u16;
typedef __attribute__((ext_vector_type(8))) short bf16x8;
typedef __attribute__((ext_vector_type(8))) unsigned short u16x8;
typedef __attribute__((ext_vector_type(4))) float f32x4;

#define AS1 __attribute__((address_space(1)))
#define AS3 __attribute__((address_space(3)))

__device__ __forceinline__ float b2f(u16 h) {
  union { u32 u; float f; } v; v.u = ((u32)h) << 16; return v.f;
}
__device__ __forceinline__ u16 f2bf(float f) {
  union { u32 u; float f; } v; v.f = f;
  u32 lsb = (v.u >> 16) & 1u;
  v.u += 0x7FFFu + lsb;
  return (u16)(v.u >> 16);
}

__device__ __forceinline__ float read_pos(const void* p, int s, int mode) {
  if (mode == 1) return (float)(int)(((const unsigned long long*)p)[s]);
  if (mode == 2) return ((const float*)p)[s];
  return (float)(((const int*)p)[s]);
}

__global__ void possniff_kernel(const u32* __restrict__ pw, int* __restrict__ mode) {
  int m = 0;
  if (pw[1] == 1u && pw[2] == 2u && pw[3] == 3u) m = 0;
  else if (pw[2] == 1u && pw[4] == 2u && pw[6] == 3u) m = 1;
  else if (pw[1] == 0x3F800000u) m = 2;
  *mode = m;
}

// ============================================================
__global__ __launch_bounds__(256) void cvt_kernel(const float* __restrict__ in,
                                                  u16* __restrict__ out, int n4) {
  int i = blockIdx.x * 256 + threadIdx.x;
  int stride = gridDim.x * 256;
  for (; i < n4; i += stride) {
    float4 v = *(const float4*)(in + (size_t)i * 4);
    ushort4 o = make_ushort4(f2bf(v.x), f2bf(v.y), f2bf(v.z), f2bf(v.w));
    *(ushort4*)(out + (size_t)i * 4) = o;
  }
}

// ============================================================
// Fused Q/K/V projection GEMM: sel = blockIdx.x>>3 picks weight+dst.
// sel 0,1 -> [B,H,S,64]; sel 2 -> V transposed [B,H,64,S].
// ============================================================
__global__ __launch_bounds__(256) void gemm_qkv(const u16* __restrict__ A,
                                                const u16* __restrict__ qw,
                                                const u16* __restrict__ kw,
                                                const u16* __restrict__ vw,
                                                u16* __restrict__ Qb,
                                                u16* __restrict__ Kb,
                                                u16* __restrict__ Vtb) {
  __shared__ u16 As[128 * 32];
  __shared__ u16 Bs[128 * 32];
  const int sel = blockIdx.x >> 3;
  const u16* W = (sel == 0) ? qw : (sel == 1 ? kw : vw);
  u16* C = (sel == 0) ? Qb : (sel == 1 ? Kb : Vtb);
  const int n0 = (blockIdx.x & 7) * 128;
  const int m0 = blockIdx.y * 128;

  const int tid = threadIdx.x;
  const int wave = tid >> 6;
  const int lane = tid & 63;
  const int wm = wave >> 1;
  const int wn = wave & 1;
  const int fl = lane & 15;
  const int kq = lane >> 4;

  const u16* Ag = A + (size_t)m0 * DM;
  const u16* Wg = W + (size_t)n0 * DM;

  f32x4 acc[4][4] = {};

  for (int k0 = 0; k0 < DM; k0 += 32) {
    __syncthreads();
#pragma unroll
    for (int j = 0; j < 2; ++j) {
      int row = wave * 32 + j * 16 + (lane >> 2);
      int sc = (lane & 3) * 8;
      __builtin_amdgcn_global_load_lds(
          (const AS1 void*)(Ag + (size_t)row * DM + k0 + sc),
          (AS3 void*)(As + wave * 1024 + j * 512), 16, 0, 0);
      __builtin_amdgcn_global_load_lds(
          (const AS1 void*)(Wg + (size_t)row * DM + k0 + sc),
          (AS3 void*)(Bs + wave * 1024 + j * 512), 16, 0, 0);
    }
    __syncthreads();

    bf16x8 af[4], bfr[4];
#pragma unroll
    for (int m = 0; m < 4; ++m)
      af[m] = *(const bf16x8*)&As[(wm * 64 + m * 16 + fl) * 32 + kq * 8];
#pragma unroll
    for (int n = 0; n < 4; ++n)
      bfr[n] = *(const bf16x8*)&Bs[(wn * 64 + n * 16 + fl) * 32 + kq * 8];
#pragma unroll
    for (int m = 0; m < 4; ++m)
#pragma unroll
      for (int n = 0; n < 4; ++n)
        acc[m][n] = __builtin_amdgcn_mfma_f32_16x16x32_bf16(af[m], bfr[n],
                                                            acc[m][n], 0, 0, 0);
  }

#pragma unroll
  for (int m = 0; m < 4; ++m) {
#pragma unroll
    for (int n = 0; n < 4; ++n) {
      int gcol = n0 + wn * 64 + n * 16 + fl;
#pragma unroll
      for (int r = 0; r < 4; ++r) {
        int grow = m0 + wm * 64 + m * 16 + kq * 4 + r;
        float v = acc[m][n][r];
        int b = grow >> 11, s = grow & (SEQ - 1);
        int h = gcol >> 6, d = gcol & 63;
        if (sel < 2)
          C[((size_t)(b * NH + h) * SEQ + s) * DH + d] = f2bf(v);
        else
          C[((size_t)(b * NH + h) * DH + d) * SEQ + s] = f2bf(v);
      }
    }
  }
}

// ============================================================
// O-projection GEMM: fp32 out C[m*1024+n]
// ============================================================
__global__ __launch_bounds__(256) void gemm_o(const u16* __restrict__ A,
                                              const u16* __restrict__ W,
                                              float* __restrict__ Cf) {
  __shared__ u16 As[128 * 32];
  __shared__ u16 Bs[128 * 32];
  const int tid = threadIdx.x;
  const int wave = tid >> 6;
  const int lane = tid & 63;
  const int wm = wave >> 1;
  const int wn = wave & 1;
  const int n0 = blockIdx.x * 128;
  const int m0 = blockIdx.y * 128;
  const int fl = lane & 15;
  const int kq = lane >> 4;

  const u16* Ag = A + (size_t)m0 * DM;
  const u16* Wg = W + (size_t)n0 * DM;

  f32x4 acc[4][4] = {};

  for (int k0 = 0; k0 < DM; k0 += 32) {
    __syncthreads();
#pragma unroll
    for (int j = 0; j < 2; ++j) {
      int row = wave * 32 + j * 16 + (lane >> 2);
      int sc = (lane & 3) * 8;
      __builtin_amdgcn_global_load_lds(
          (const AS1 void*)(Ag + (size_t)row * DM + k0 + sc),
          (AS3 void*)(As + wave * 1024 + j * 512), 16, 0, 0);
      __builtin_amdgcn_global_load_lds(
          (const AS1 void*)(Wg + (size_t)row * DM + k0 + sc),
          (AS3 void*)(Bs + wave * 1024 + j * 512), 16, 0, 0);
    }
    __syncthreads();

    bf16x8 af[4], bfr[4];
#pragma unroll
    for (int m = 0; m < 4; ++m)
      af[m] = *(const bf16x8*)&As[(wm * 64 + m * 16 + fl) * 32 + kq * 8];
#pragma unroll
    for (int n = 0; n < 4; ++n)
      bfr[n] = *(const bf16x8*)&Bs[(wn * 64 + n * 16 + fl) * 32 + kq * 8];
#pragma unroll
    for (int m = 0; m < 4; ++m)
#pragma unroll
      for (int n = 0; n < 4; ++n)
        acc[m][n] = __builtin_amdgcn_mfma_f32_16x16x32_bf16(af[m], bfr[n],
                                                            acc[m][n], 0, 0, 0);
  }

#pragma unroll
  for (int m = 0; m < 4; ++m)
#pragma unroll
    for (int n = 0; n < 4; ++n) {
      int gcol = n0 + wn * 64 + n * 16 + fl;
#pragma unroll
      for (int r = 0; r < 4; ++r) {
        int grow = m0 + wm * 64 + m * 16 + kq * 4 + r;
        Cf[(size_t)grow * DM + gcol] = acc[m][n][r];
      }
    }
}

// ============================================================
// RoPE c9 (unchanged)
// ============================================================
__global__ __launch_bounds__(256) void rope_c9(u16* __restrict__ Q,
                                               u16* __restrict__ K,
                                               const void* __restrict__ pos,
                                               const int* __restrict__ pmode) {
  int idx = blockIdx.x * blockDim.x + threadIdx.x;
  int i = idx & 31;
  int s = (idx >> 5) & (SEQ - 1);
  int bh = idx >> 16;
  float p = read_pos(pos, s, *pmode);
  float inv = powf(10000.0f, -(float)i * (1.0f / 32.0f));
  float ang = p * inv;
  float c, sn;
  sincosf(ang, &c, &sn);
  size_t base = ((size_t)bh * SEQ + s) * DH + 2 * i;
  float q1 = b2f(Q[base]), q2 = b2f(Q[base + 1]);
  Q[base]     = f2bf(q1 * c + q2 * sn);
  Q[base + 1] = f2bf(-q1 * sn + q2 * c);
  float k1 = b2f(K[base]), k2 = b2f(K[base + 1]);
  K[base]     = f2bf(k1 * c + k2 * sn);
  K[base + 1] = f2bf(-k1 * sn + k2 * c);
}

// ============================================================
// MFMA flash attention v4:
//  - paired q-tiles (qt, 15-qt): every block = exactly 17 K-tile steps
//  - KVBLK=128: half the barriers per unit work
//  - K/V staged via global_load_lds w/ pre-swizzled global source
//  - Q staged per-wave into row-aligned overlay of Ps (no barrier)
//  - fixed-max softmax (M=14), l via ones-MFMA (verified r21)
//  LDS: Ks 16KB + Vs 16KB + Ps 32KB = 64KB -> 2 blocks/CU
// ============================================================
__global__ __launch_bounds__(256) void attn_mfma(const u16* __restrict__ Q,
                                                 const u16* __restrict__ K,
                                                 const u16* __restrict__ Vt_g,
                                                 u16* __restrict__ AO) {
  __shared__ u16 Ks[KVBLK * 64];    // [kpos][d]
  __shared__ u16 Vs[64 * KVBLK];    // [d][kpos]
  __shared__ u16 Ps[QBLK * 128];    // [q][kpos]; Q overlay in cols 0..63

  const int bx = blockIdx.x;        // 0..7
  const int bh = blockIdx.y;
  const int tid = threadIdx.x;
  const int w = tid >> 6, lane = tid & 63;
  const int fl = lane & 15, kq = lane >> 4;
  const int fl7 = fl & 7;
  const u16* Qg = Q + (size_t)bh * SEQ * DH;
  const u16* Kg = K + (size_t)bh * SEQ * DH;
  const u16* Vg = Vt_g + (size_t)bh * DH * SEQ;
  const int b = bh >> 4, h = bh & 15;

  const short ONE = 0x3F80;
  const bf16x8 ones = {ONE, ONE, ONE, ONE, ONE, ONE, ONE, ONE};
  const float C1 = 0.125f * 1.4426950408889634f;
  const float C2 = 14.0f * 1.4426950408889634f;

  for (int ph = 0; ph < 2; ++ph) {
    const int qt = ph ? bx : (15 - bx);
    const int q0 = qt * QBLK;

    // ---- stage this wave's 32 Q rows into Ps cols 0..63 (swizzled) ----
#pragma unroll
    for (int it = 0; it < 4; ++it) {
      int idx = it * 64 + lane;          // 0..255
      int row = w * 32 + (idx >> 3);
      int oct = idx & 7;
      u16x8 v = *(const u16x8*)(Qg + (size_t)(q0 + row) * DH + oct * 8);
      *(u16x8*)&Ps[row * 128 + ((oct ^ (row & 7)) << 3)] = v;
    }
    bf16x8 aq[2][2];
#pragma unroll
    for (int m = 0; m < 2; ++m) {
      int qrow = w * 32 + m * 16 + fl;
#pragma unroll
      for (int c = 0; c < 2; ++c)
        aq[m][c] = *(const bf16x8*)&Ps[qrow * 128 + (((kq + 4 * c) ^ fl7) << 3)];
    }

    f32x4 o_acc[2][4] = {};
    f32x4 l_acc[2] = {};

    for (int kt = 0; kt <= qt; ++kt) {
      const int kb = kt * KVBLK;
      __syncthreads();   // prior tile K/V reads done (drains vmcnt too)

      // ---- K stage: wave w rows [w*32+it*8, +8), source pre-swizzled ----
#pragma unroll
      for (int it = 0; it < 4; ++it) {
        int rowbase = w * 32 + it * 8;
        int row = rowbase + (lane >> 3);
        int oct = (lane & 7) ^ (row & 7);
        __builtin_amdgcn_global_load_lds(
            (const AS1 void*)(Kg + (size_t)(kb + row) * DH + oct * 8),
            (AS3 void*)(Ks + rowbase * 64), 16, 0, 0);
      }
      // ---- V stage: wave w d-rows [w*16+it*4, +4) ----
#pragma unroll
      for (int it = 0; it < 4; ++it) {
        int rowbase = w * 16 + it * 4;
        int row = rowbase + (lane >> 4);
        int s16 = lane & 15;
        int oct = (s16 & 8) | ((s16 & 7) ^ (row & 7));
        __builtin_amdgcn_global_load_lds(
            (const AS1 void*)(Vg + (size_t)row * SEQ + kb + oct * 8),
            (AS3 void*)(Vs + rowbase * 128), 16, 0, 0);
      }
      __syncthreads();

      // ---- QK^T: two 16x128 strips ----
      f32x4 sA[8] = {}, sB[8] = {};
#pragma unroll
      for (int n = 0; n < 8; ++n) {
        int row = n * 16 + fl;
        bf16x8 b0 = *(const bf16x8*)&Ks[row * 64 + ((kq ^ fl7) << 3)];
        bf16x8 b1 = *(const bf16x8*)&Ks[row * 64 + (((kq + 4) ^ fl7) << 3)];
        sA[n] = __builtin_amdgcn_mfma_f32_16x16x32_bf16(aq[0][0], b0, sA[n], 0, 0, 0);
        sA[n] = __builtin_amdgcn_mfma_f32_16x16x32_bf16(aq[0][1], b1, sA[n], 0, 0, 0);
        sB[n] = __builtin_amdgcn_mfma_f32_16x16x32_bf16(aq[1][0], b0, sB[n], 0, 0, 0);
        sB[n] = __builtin_amdgcn_mfma_f32_16x16x32_bf16(aq[1][1], b1, sB[n], 0, 0, 0);
      }

      // ---- fixed-max softmax + P staging ----
      const bool nm = (kt == qt);
#pragma unroll
      for (int m = 0; m < 2; ++m) {
#pragma unroll
        for (int n = 0; n < 8; ++n)
#pragma unroll
          for (int r = 0; r < 4; ++r) {
            float sv = (m == 0) ? sA[n][r] : sB[n][r];
            float p;
            if (nm) {
              int qrow = q0 + w * 32 + m * 16 + kq * 4 + r;
              int kcol = kb + n * 16 + fl;
              p = (kcol > qrow) ? 0.f : exp2f(sv * C1 - C2);
            } else {
              p = exp2f(sv * C1 - C2);
            }
            int rr = w * 32 + m * 16 + kq * 4 + r;
            int slot = n * 2 + (fl >> 3);
            Ps[rr * 128 + (((slot ^ (rr & 7)) << 3) | fl7)] = f2bf(p);
          }
      }

      // ---- PV + denominators (P frags per k-chunk, V frags shared) ----
#pragma unroll
      for (int c = 0; c < 4; ++c) {
        int sl = (c * 4 + kq) ^ fl7;
        bf16x8 ap0 = *(const bf16x8*)&Ps[(w * 32 + fl) * 128 + (sl << 3)];
        bf16x8 ap1 = *(const bf16x8*)&Ps[(w * 32 + 16 + fl) * 128 + (sl << 3)];
        l_acc[0] = __builtin_amdgcn_mfma_f32_16x16x32_bf16(ap0, ones, l_acc[0], 0, 0, 0);
        l_acc[1] = __builtin_amdgcn_mfma_f32_16x16x32_bf16(ap1, ones, l_acc[1], 0, 0, 0);
#pragma unroll
        for (int n = 0; n < 4; ++n) {
          bf16x8 vb = *(const bf16x8*)&Vs[(n * 16 + fl) * 128 + (sl << 3)];
          o_acc[0][n] = __builtin_amdgcn_mfma_f32_16x16x32_bf16(ap0, vb, o_acc[0][n], 0, 0, 0);
          o_acc[1][n] = __builtin_amdgcn_mfma_f32_16x16x32_bf16(ap1, vb, o_acc[1][n], 0, 0, 0);
        }
      }
    }

    // ---- epilogue for this q-tile ----
#pragma unroll
    for (int m = 0; m < 2; ++m)
#pragma unroll
      for (int r = 0; r < 4; ++r) {
        float invl = 1.0f / l_acc[m][r];
        int qrow = q0 + w * 32 + m * 16 + kq * 4 + r;
#pragma unroll
        for (int n = 0; n < 4; ++n) {
          int d = n * 16 + fl;
          AO[((size_t)(b * SEQ + qrow)) * DM + h * DH + d] = f2bf(o_acc[m][n][r] * invl);
        }
      }
  }
}

// ============================================================
extern "C" void kernel_launch(void* const* d_in, const int* in_sizes, int n_in,
                              void* d_out, int out_size, void* d_ws, size_t ws_size,
                              hipStream_t stream) {
  int xi = -1, pi = -1, widx[8], nw = 0;
  for (int i = 0; i < n_in; ++i) {
    if (in_sizes[i] == BATCH * SEQ * DM) xi = i;
    else if (in_sizes[i] == SEQ) pi = i;
    else if (in_sizes[i] == DM * DM && nw < 8) widx[nw++] = i;
  }
  if (xi < 0) xi = 0;
  if (pi < 0) pi = 1;

  const float* x   = (const float*)d_in[xi];
  const void*  pos = d_in[pi];
  const float* q_w = (const float*)d_in[widx[0]];
  const float* k_w = (const float*)d_in[widx[1]];
  const float* v_w = (const float*)d_in[widx[2]];
  const float* o_w = (const float*)d_in[widx[3]];
  float* out = (float*)d_out;

  const size_t elems = (size_t)BATCH * SEQ * DM;   // 8388608
  const size_t welems = (size_t)DM * DM;           // 1048576
  u16* Qb  = (u16*)d_ws;
  u16* Kb  = Qb + elems;
  u16* Vtb = Kb + elems;   // [B,H,D,S]
  u16* AOb = Vtb + elems;
  u16* xb  = AOb + elems;
  u16* qwb = xb + elems;
  u16* kwb = qwb + welems;
  u16* vwb = kwb + welems;
  u16* owb = vwb + welems;
  int* pmode = (int*)(owb + welems);

  hipLaunchKernelGGL(possniff_kernel, dim3(1), dim3(1), 0, stream,
                     (const u32*)pos, pmode);

  hipLaunchKernelGGL(cvt_kernel, dim3(2048), dim3(256), 0, stream,
                     x, xb, (int)(elems / 4));
  hipLaunchKernelGGL(cvt_kernel, dim3(1024), dim3(256), 0, stream,
                     q_w, qwb, (int)(welems / 4));
  hipLaunchKernelGGL(cvt_kernel, dim3(1024), dim3(256), 0, stream,
                     k_w, kwb, (int)(welems / 4));
  hipLaunchKernelGGL(cvt_kernel, dim3(1024), dim3(256), 0, stream,
                     v_w, vwb, (int)(welems / 4));
  hipLaunchKernelGGL(cvt_kernel, dim3(1024), dim3(256), 0, stream,
                     o_w, owb, (int)(welems / 4));

  // fused Q/K/V projections
  hipLaunchKernelGGL(gemm_qkv, dim3(24, (BATCH * SEQ) / 128), dim3(256), 0,
                     stream, xb, qwb, kwb, vwb, Qb, Kb, Vtb);

  int rope_threads = BATCH * NH * SEQ * 32;
  hipLaunchKernelGGL(rope_c9, dim3(rope_threads / 256), dim3(256), 0, stream,
                     Qb, Kb, pos, pmode);

  hipLaunchKernelGGL(attn_mfma, dim3(SEQ / QBLK / 2, BATCH * NH), dim3(256), 0,
                     stream, Qb, Kb, Vtb, AOb);

  hipLaunchKernelGGL(gemm_o, dim3(DM / 128, (BATCH * SEQ) / 128), dim3(256), 0,
                     stream, AOb, owb, out);
}